// Round 4
// baseline (104.725 us; speedup 1.0000x reference)
//
#include <hip/hip_runtime.h>

// Algebraic reduction of ECCConv + GlobalSumPool + Dense:
//   out = relu( (sum_e msg[e] + colsum(x)@W_root + N*b_conv) @ W_dense + b_dense )
//   sum_e msg[e,h] = sum_{f,s} T[f,s]*W_kn[s,f*32+h] + sum_f u[f]*b_kn[f*32+h]
//   T[f,s] = sum_e x[src[e],f]*ea[e,s],  u[f] = sum_e x[src[e],f]
//
// ws layout (float): [0..63] T[f*4+s], [64..79] u[f], [80..95] colsum[f]
//
// NOTE: harness delivers integer inputs as int32 (edge_index is int32 here,
// despite the reference's int64) — reading it as int64 OOB-faulted in R3.

#define F_IN 16
#define F_OUT 32
#define EDGE_BLOCKS 128
#define X_BLOCKS 32
#define THREADS 256

__global__ void zero_ws(float* __restrict__ ws) {
    int t = threadIdx.x;
    if (t < 96) ws[t] = 0.0f;
}

__global__ __launch_bounds__(THREADS) void reduce_kernel(
    const float* __restrict__ x, const int* __restrict__ ei,
    const float* __restrict__ ea, float* __restrict__ ws, int N, int E) {
    __shared__ float lred[4][96];
    const int bid  = blockIdx.x;
    const int tid  = threadIdx.x;
    const int wave = tid >> 6;
    const int lane = tid & 63;

    if (bid < EDGE_BLOCKS) {
        // ---- edge reduction: T[16][4] and u[16] ----
        float acc[80];
        #pragma unroll
        for (int i = 0; i < 80; ++i) acc[i] = 0.0f;

        const int gtid   = bid * THREADS + tid;
        const int stride = EDGE_BLOCKS * THREADS;
        for (int e = gtid; e < E; e += stride) {
            const int s = ei[(size_t)E + e];           // src row (edge_index[1])
            const float4 a = *reinterpret_cast<const float4*>(ea + (size_t)e * 4);
            const float4* xr = reinterpret_cast<const float4*>(x + (size_t)s * 16);
            float4 v0 = xr[0], v1 = xr[1], v2 = xr[2], v3 = xr[3];
            float xs[16];
            xs[0]=v0.x; xs[1]=v0.y; xs[2]=v0.z; xs[3]=v0.w;
            xs[4]=v1.x; xs[5]=v1.y; xs[6]=v1.z; xs[7]=v1.w;
            xs[8]=v2.x; xs[9]=v2.y; xs[10]=v2.z; xs[11]=v2.w;
            xs[12]=v3.x; xs[13]=v3.y; xs[14]=v3.z; xs[15]=v3.w;
            #pragma unroll
            for (int f = 0; f < 16; ++f) {
                const float v = xs[f];
                acc[64 + f] += v;
                acc[f*4+0] = fmaf(v, a.x, acc[f*4+0]);
                acc[f*4+1] = fmaf(v, a.y, acc[f*4+1]);
                acc[f*4+2] = fmaf(v, a.z, acc[f*4+2]);
                acc[f*4+3] = fmaf(v, a.w, acc[f*4+3]);
            }
        }
        // wave butterfly reduce each of the 80 values
        #pragma unroll
        for (int i = 0; i < 80; ++i) {
            float v = acc[i];
            #pragma unroll
            for (int m = 1; m < 64; m <<= 1) v += __shfl_xor(v, m, 64);
            if (lane == 0) lred[wave][i] = v;
        }
        __syncthreads();
        if (tid < 80) {
            float v = lred[0][tid] + lred[1][tid] + lred[2][tid] + lred[3][tid];
            atomicAdd(&ws[tid], v);
        }
    } else {
        // ---- column sums of x ----
        float cs[16];
        #pragma unroll
        for (int i = 0; i < 16; ++i) cs[i] = 0.0f;

        const int gtid   = (bid - EDGE_BLOCKS) * THREADS + tid;
        const int stride = X_BLOCKS * THREADS;
        for (int r = gtid; r < N; r += stride) {
            const float4* xr = reinterpret_cast<const float4*>(x + (size_t)r * 16);
            float4 v0 = xr[0], v1 = xr[1], v2 = xr[2], v3 = xr[3];
            cs[0]+=v0.x; cs[1]+=v0.y; cs[2]+=v0.z;  cs[3]+=v0.w;
            cs[4]+=v1.x; cs[5]+=v1.y; cs[6]+=v1.z;  cs[7]+=v1.w;
            cs[8]+=v2.x; cs[9]+=v2.y; cs[10]+=v2.z; cs[11]+=v2.w;
            cs[12]+=v3.x; cs[13]+=v3.y; cs[14]+=v3.z; cs[15]+=v3.w;
        }
        #pragma unroll
        for (int i = 0; i < 16; ++i) {
            float v = cs[i];
            #pragma unroll
            for (int m = 1; m < 64; m <<= 1) v += __shfl_xor(v, m, 64);
            if (lane == 0) lred[wave][i] = v;
        }
        __syncthreads();
        if (tid < 16) {
            float v = lred[0][tid] + lred[1][tid] + lred[2][tid] + lred[3][tid];
            atomicAdd(&ws[80 + tid], v);
        }
    }
}

__global__ void finalize(
    const float* __restrict__ ws,
    const float* __restrict__ W_kn, const float* __restrict__ b_kn,
    const float* __restrict__ W_root, const float* __restrict__ b_conv,
    const float* __restrict__ W_dense, const float* __restrict__ b_dense,
    float* __restrict__ out, int N) {
    __shared__ float pooled[32];
    const int t = threadIdx.x;
    if (t < 32) {
        float p = (float)N * b_conv[t];
        #pragma unroll
        for (int f = 0; f < 16; ++f) {
            float tsum = 0.0f;
            #pragma unroll
            for (int s = 0; s < 4; ++s)
                tsum = fmaf(ws[f*4+s], W_kn[s*512 + f*32 + t], tsum);
            p += tsum;
            p = fmaf(ws[64+f], b_kn[f*32+t], p);
            p = fmaf(ws[80+f], W_root[f*32+t], p);
        }
        pooled[t] = p;
    }
    __syncthreads();
    if (t < 3) {
        float o = b_dense[t];
        #pragma unroll
        for (int h = 0; h < 32; ++h) o = fmaf(pooled[h], W_dense[h*3+t], o);
        out[t] = fmaxf(o, 0.0f);
    }
}

extern "C" void kernel_launch(void* const* d_in, const int* in_sizes, int n_in,
                              void* d_out, int out_size, void* d_ws, size_t ws_size,
                              hipStream_t stream) {
    const float* x       = (const float*)d_in[0];
    const int*   ei      = (const int*)d_in[1];     // int32 (harness convention)
    const float* ea      = (const float*)d_in[2];
    const float* W_kn    = (const float*)d_in[3];
    const float* b_kn    = (const float*)d_in[4];
    const float* W_root  = (const float*)d_in[5];
    const float* b_conv  = (const float*)d_in[6];
    const float* W_dense = (const float*)d_in[7];
    const float* b_dense = (const float*)d_in[8];
    float* ws  = (float*)d_ws;
    float* out = (float*)d_out;

    const int N = in_sizes[0] / F_IN;   // 50000
    const int E = in_sizes[1] / 2;      // 400000

    hipLaunchKernelGGL(zero_ws, dim3(1), dim3(96), 0, stream, ws);
    hipLaunchKernelGGL(reduce_kernel, dim3(EDGE_BLOCKS + X_BLOCKS), dim3(THREADS),
                       0, stream, x, ei, ea, ws, N, E);
    hipLaunchKernelGGL(finalize, dim3(1), dim3(64), 0, stream,
                       ws, W_kn, b_kn, W_root, b_conv, W_dense, b_dense, out, N);
}

// Round 5
// 89.346 us; speedup vs baseline: 1.1721x; 1.1721x over previous
//
#include <hip/hip_runtime.h>

// Algebraic reduction of ECCConv + GlobalSumPool + Dense:
//   out = relu( (sum_e msg[e] + colsum(x)@W_root + N*b_conv) @ W_dense + b_dense )
//   sum_e msg[e,h] = sum_{f,s} T[f,s]*W_kn[s,f*32+h] + sum_f u[f]*b_kn[f*32+h]
//   T[f,s] = sum_e x[src[e],f]*ea[e,s],  u[f] = sum_e x[src[e],f]
//
// Structure (2 graph nodes, was 3):
//   partial_kernel: 160 blocks, each writes a private 96-float slot in ws
//     (plain stores -> no zero-init kernel, no global atomics)
//   final_kernel:   1 block sums slots, applies weights, writes out[3]
//
// edge_index arrives as int32 (harness integer convention).

#define F_IN 16
#define EDGE_BLOCKS 128
#define X_BLOCKS 32
#define TOTAL_BLOCKS (EDGE_BLOCKS + X_BLOCKS)
#define THREADS 512

__global__ __launch_bounds__(THREADS) void partial_kernel(
    const float* __restrict__ x, const int* __restrict__ ei,
    const float* __restrict__ ea, float* __restrict__ ws, int N, int E) {
    __shared__ float lred[96];
    const int bid  = blockIdx.x;
    const int tid  = threadIdx.x;
    const int lane = tid & 63;
    const bool b5 = (lane & 32) != 0, b4 = (lane & 16) != 0;
    const bool b3 = (lane & 8)  != 0, b2 = (lane & 4)  != 0;

    if (tid < 96) lred[tid] = 0.0f;
    __syncthreads();

    if (bid < EDGE_BLOCKS) {
        // ---- edge partials: T[16][4] (acc[0..63], f*4+s) and u[16] (acc[64..79]) ----
        float acc[80];
        #pragma unroll
        for (int i = 0; i < 80; ++i) acc[i] = 0.0f;

        const int gtid   = bid * THREADS + tid;
        const int stride = EDGE_BLOCKS * THREADS;
        for (int e = gtid; e < E; e += stride) {
            const int s = ei[(size_t)E + e];           // src row (edge_index[1])
            const float4 a = *reinterpret_cast<const float4*>(ea + (size_t)e * 4);
            const float4* xr = reinterpret_cast<const float4*>(x + (size_t)s * 16);
            const float4 v0 = xr[0], v1 = xr[1], v2 = xr[2], v3 = xr[3];
            const float xs[16] = {v0.x,v0.y,v0.z,v0.w, v1.x,v1.y,v1.z,v1.w,
                                  v2.x,v2.y,v2.z,v2.w, v3.x,v3.y,v3.z,v3.w};
            #pragma unroll
            for (int f = 0; f < 16; ++f) {
                const float v = xs[f];
                acc[64 + f] += v;
                acc[f*4+0] = fmaf(v, a.x, acc[f*4+0]);
                acc[f*4+1] = fmaf(v, a.y, acc[f*4+1]);
                acc[f*4+2] = fmaf(v, a.z, acc[f*4+2]);
                acc[f*4+3] = fmaf(v, a.w, acc[f*4+3]);
            }
        }

        // ---- folding wave reduction: 85 shfl + 85 adds (vs 480+480 butterfly) ----
        // After fold k over lane-bit b, each lane keeps half the values, summed
        // with its partner's copy of the SAME values. After 4 folds each 4-lane
        // group holds 5 values: value index = 40*b5+20*b4+10*b3+5*b2 + i.
        #pragma unroll
        for (int i = 0; i < 40; ++i) {
            const float sendv = b5 ? acc[i] : acc[i+40];
            const float keepv = b5 ? acc[i+40] : acc[i];
            acc[i] = keepv + __shfl_xor(sendv, 32, 64);
        }
        #pragma unroll
        for (int i = 0; i < 20; ++i) {
            const float sendv = b4 ? acc[i] : acc[i+20];
            const float keepv = b4 ? acc[i+20] : acc[i];
            acc[i] = keepv + __shfl_xor(sendv, 16, 64);
        }
        #pragma unroll
        for (int i = 0; i < 10; ++i) {
            const float sendv = b3 ? acc[i] : acc[i+10];
            const float keepv = b3 ? acc[i+10] : acc[i];
            acc[i] = keepv + __shfl_xor(sendv, 8, 64);
        }
        #pragma unroll
        for (int i = 0; i < 5; ++i) {
            const float sendv = b2 ? acc[i] : acc[i+5];
            const float keepv = b2 ? acc[i+5] : acc[i];
            acc[i] = keepv + __shfl_xor(sendv, 4, 64);
        }
        #pragma unroll
        for (int i = 0; i < 5; ++i) {
            acc[i] += __shfl_xor(acc[i], 2, 64);
            acc[i] += __shfl_xor(acc[i], 1, 64);
        }
        if ((lane & 3) == 0) {
            const int vbase = (b5?40:0) + (b4?20:0) + (b3?10:0) + (b2?5:0);
            #pragma unroll
            for (int i = 0; i < 5; ++i) atomicAdd(&lred[vbase + i], acc[i]);
        }
        __syncthreads();
        if (tid < 80) ws[(size_t)bid * 96 + tid] = lred[tid];
    } else {
        // ---- column sums of x: cs[16] ----
        float cs[16];
        #pragma unroll
        for (int i = 0; i < 16; ++i) cs[i] = 0.0f;

        const int gtid   = (bid - EDGE_BLOCKS) * THREADS + tid;
        const int stride = X_BLOCKS * THREADS;
        for (int r = gtid; r < N; r += stride) {
            const float4* xr = reinterpret_cast<const float4*>(x + (size_t)r * 16);
            const float4 v0 = xr[0], v1 = xr[1], v2 = xr[2], v3 = xr[3];
            cs[0]+=v0.x; cs[1]+=v0.y; cs[2]+=v0.z;  cs[3]+=v0.w;
            cs[4]+=v1.x; cs[5]+=v1.y; cs[6]+=v1.z;  cs[7]+=v1.w;
            cs[8]+=v2.x; cs[9]+=v2.y; cs[10]+=v2.z; cs[11]+=v2.w;
            cs[12]+=v3.x; cs[13]+=v3.y; cs[14]+=v3.z; cs[15]+=v3.w;
        }
        // fold 16 values: value index = 8*b5+4*b4+2*b3+b2 = (lane>>2)
        #pragma unroll
        for (int i = 0; i < 8; ++i) {
            const float sendv = b5 ? cs[i] : cs[i+8];
            const float keepv = b5 ? cs[i+8] : cs[i];
            cs[i] = keepv + __shfl_xor(sendv, 32, 64);
        }
        #pragma unroll
        for (int i = 0; i < 4; ++i) {
            const float sendv = b4 ? cs[i] : cs[i+4];
            const float keepv = b4 ? cs[i+4] : cs[i];
            cs[i] = keepv + __shfl_xor(sendv, 16, 64);
        }
        #pragma unroll
        for (int i = 0; i < 2; ++i) {
            const float sendv = b3 ? cs[i] : cs[i+2];
            const float keepv = b3 ? cs[i+2] : cs[i];
            cs[i] = keepv + __shfl_xor(sendv, 8, 64);
        }
        {
            const float sendv = b2 ? cs[0] : cs[1];
            const float keepv = b2 ? cs[1] : cs[0];
            cs[0] = keepv + __shfl_xor(sendv, 4, 64);
        }
        cs[0] += __shfl_xor(cs[0], 2, 64);
        cs[0] += __shfl_xor(cs[0], 1, 64);
        if ((lane & 3) == 0) atomicAdd(&lred[80 + (lane >> 2)], cs[0]);
        __syncthreads();
        if (tid < 16) ws[(size_t)bid * 96 + 80 + tid] = lred[80 + tid];
    }
}

__global__ __launch_bounds__(128) void final_kernel(
    const float* __restrict__ slots,
    const float* __restrict__ W_kn, const float* __restrict__ b_kn,
    const float* __restrict__ W_root, const float* __restrict__ b_conv,
    const float* __restrict__ W_dense, const float* __restrict__ b_dense,
    float* __restrict__ out, int N) {
    __shared__ float red[96];
    __shared__ float pooled[32];
    const int t = threadIdx.x;
    if (t < 96) {
        float s = 0.0f;
        if (t < 80) {
            for (int b = 0; b < EDGE_BLOCKS; ++b) s += slots[(size_t)b * 96 + t];
        } else {
            for (int b = EDGE_BLOCKS; b < TOTAL_BLOCKS; ++b) s += slots[(size_t)b * 96 + t];
        }
        red[t] = s;
    }
    __syncthreads();
    if (t < 32) {
        float p = (float)N * b_conv[t];
        #pragma unroll
        for (int f = 0; f < 16; ++f) {
            float tsum = 0.0f;
            #pragma unroll
            for (int s = 0; s < 4; ++s)
                tsum = fmaf(red[f*4+s], W_kn[s*512 + f*32 + t], tsum);
            p += tsum;
            p = fmaf(red[64+f], b_kn[f*32+t], p);
            p = fmaf(red[80+f], W_root[f*32+t], p);
        }
        pooled[t] = p;
    }
    __syncthreads();
    if (t < 3) {
        float o = b_dense[t];
        #pragma unroll
        for (int h = 0; h < 32; ++h) o = fmaf(pooled[h], W_dense[h*3+t], o);
        out[t] = fmaxf(o, 0.0f);
    }
}

extern "C" void kernel_launch(void* const* d_in, const int* in_sizes, int n_in,
                              void* d_out, int out_size, void* d_ws, size_t ws_size,
                              hipStream_t stream) {
    const float* x       = (const float*)d_in[0];
    const int*   ei      = (const int*)d_in[1];     // int32 (harness convention)
    const float* ea      = (const float*)d_in[2];
    const float* W_kn    = (const float*)d_in[3];
    const float* b_kn    = (const float*)d_in[4];
    const float* W_root  = (const float*)d_in[5];
    const float* b_conv  = (const float*)d_in[6];
    const float* W_dense = (const float*)d_in[7];
    const float* b_dense = (const float*)d_in[8];
    float* ws  = (float*)d_ws;
    float* out = (float*)d_out;

    const int N = in_sizes[0] / F_IN;   // 50000
    const int E = in_sizes[1] / 2;      // 400000

    hipLaunchKernelGGL(partial_kernel, dim3(TOTAL_BLOCKS), dim3(THREADS),
                       0, stream, x, ei, ea, ws, N, E);
    hipLaunchKernelGGL(final_kernel, dim3(1), dim3(128), 0, stream,
                       ws, W_kn, b_kn, W_root, b_conv, W_dense, b_dense, out, N);
}